// Round 1
// baseline (716.968 us; speedup 1.0000x reference)
//
#include <hip/hip_runtime.h>
#include <cstdint>
#include <cstddef>

#define FEATURE_IN 4096
#define FEATURE_OUT 4096
#define RNK 16

typedef __bf16 bf16x8_t __attribute__((ext_vector_type(8)));
typedef float f32x4_t __attribute__((ext_vector_type(4)));

// ---------------- kernel 1: x fp32 -> bf16 (8 elems/thread, 16B ld/st) -------
__global__ __launch_bounds__(256) void cvt_x_bf16(const float4* __restrict__ x,
                                                  uint16_t* __restrict__ y) {
    int i = blockIdx.x * blockDim.x + threadIdx.x;
    float4 v0 = x[2 * i];
    float4 v1 = x[2 * i + 1];
    bf16x8_t o;
    o[0] = (__bf16)v0.x; o[1] = (__bf16)v0.y; o[2] = (__bf16)v0.z; o[3] = (__bf16)v0.w;
    o[4] = (__bf16)v1.x; o[5] = (__bf16)v1.y; o[6] = (__bf16)v1.z; o[7] = (__bf16)v1.w;
    ((bf16x8_t*)y)[i] = o;
}

// -------- kernel 2: Wf[n,k] = bf16(W[n,k] + 2*sum_r A[k,r]*B[r,n]) ----------
// one thread -> 8 consecutive k for one n (coalesced W read / Wf write)
__global__ __launch_bounds__(256) void fuse_w_kernel(const float* __restrict__ w,
                                                     const float* __restrict__ la,
                                                     const float* __restrict__ lb,
                                                     uint16_t* __restrict__ wf) {
    int t = blockIdx.x * blockDim.x + threadIdx.x;       // 0 .. N*K/8-1
    int k8 = (t & (FEATURE_IN / 8 - 1)) * 8;
    int n  = t >> 9;                                     // t / (FEATURE_IN/8)
    float bcol[RNK];
#pragma unroll
    for (int r = 0; r < RNK; ++r) bcol[r] = lb[(size_t)r * FEATURE_OUT + n];
    const float4* a4 = (const float4*)(la + (size_t)k8 * RNK);
    float acc[8];
#pragma unroll
    for (int j = 0; j < 8; ++j) {
        float s = 0.f;
#pragma unroll
        for (int r4 = 0; r4 < 4; ++r4) {
            float4 av = a4[j * 4 + r4];
            s += av.x * bcol[r4 * 4 + 0] + av.y * bcol[r4 * 4 + 1] +
                 av.z * bcol[r4 * 4 + 2] + av.w * bcol[r4 * 4 + 3];
        }
        acc[j] = s;
    }
    const float4* w4 = (const float4*)(w + (size_t)n * FEATURE_IN + k8);
    float4 w0 = w4[0], w1 = w4[1];
    bf16x8_t o;
    o[0] = (__bf16)(w0.x + 2.f * acc[0]);
    o[1] = (__bf16)(w0.y + 2.f * acc[1]);
    o[2] = (__bf16)(w0.z + 2.f * acc[2]);
    o[3] = (__bf16)(w0.w + 2.f * acc[3]);
    o[4] = (__bf16)(w1.x + 2.f * acc[4]);
    o[5] = (__bf16)(w1.y + 2.f * acc[5]);
    o[6] = (__bf16)(w1.z + 2.f * acc[6]);
    o[7] = (__bf16)(w1.w + 2.f * acc[7]);
    ((bf16x8_t*)wf)[t] = o;
}

// -------- kernel 3: C[M,N] = Xb[M,K] * Wf[N,K]^T + bias, fp32 out -----------
// m97 structure: 128x128 tile, BK=32, 4 waves (2x2), 4x4 MFMA 16x16x32 each,
// global_load_lds width=16 staging.
#define BM 128
#define BN 128
#define BK 32

__global__ __launch_bounds__(256) void gemm_bt(const uint16_t* __restrict__ Au,
                                               const uint16_t* __restrict__ Bu,
                                               const float* __restrict__ bias,
                                               float* __restrict__ C,
                                               int M, int N, int K) {
    __shared__ __bf16 As[BM * BK];   // [m][k], row-major, unpadded (global_load_lds layout)
    __shared__ __bf16 Bs[BN * BK];   // [n][k]

    const __bf16* A = (const __bf16*)Au;
    const __bf16* B = (const __bf16*)Bu;

    const int wv    = threadIdx.x >> 6;
    const int lane  = threadIdx.x & 63;
    const int waveM = wv >> 1;           // 0..1
    const int waveN = wv & 1;            // 0..1
    const int m0 = blockIdx.y * BM;
    const int n0 = blockIdx.x * BN;

    // staging: per global_load_lds call, lane i covers row c*16 + (i>>2), k-offset (i&3)*8
    const int rowInCall = lane >> 2;
    const int kOff      = (lane & 3) * 8;

    const int l15  = lane & 15;
    const int quad = lane >> 4;
    const int aoff = l15 * BK + quad * 8;  // fragment read offset within a 16-row group

    f32x4_t acc[4][4];
#pragma unroll
    for (int mi = 0; mi < 4; ++mi)
#pragma unroll
        for (int ni = 0; ni < 4; ++ni)
            acc[mi][ni] = (f32x4_t)0.f;

    for (int k0 = 0; k0 < K; k0 += BK) {
        __syncthreads();   // previous iter's ds_reads done before overwrite
#pragma unroll
        for (int t = 0; t < 2; ++t) {
            const int c = wv * 2 + t;   // 0..7, wave-uniform
            const __bf16* ga = A + (size_t)(m0 + c * 16 + rowInCall) * K + (k0 + kOff);
            __builtin_amdgcn_global_load_lds((const __attribute__((address_space(1))) void*)ga,
                                             (__attribute__((address_space(3))) void*)&As[c * 512],
                                             16, 0, 0);
            const __bf16* gb = B + (size_t)(n0 + c * 16 + rowInCall) * K + (k0 + kOff);
            __builtin_amdgcn_global_load_lds((const __attribute__((address_space(1))) void*)gb,
                                             (__attribute__((address_space(3))) void*)&Bs[c * 512],
                                             16, 0, 0);
        }
        __syncthreads();   // staging drained (vmcnt(0) before barrier)

        bf16x8_t af[4], bfr[4];
#pragma unroll
        for (int mi = 0; mi < 4; ++mi)
            af[mi] = *(const bf16x8_t*)&As[(waveM * 64 + mi * 16) * BK + aoff];
#pragma unroll
        for (int ni = 0; ni < 4; ++ni)
            bfr[ni] = *(const bf16x8_t*)&Bs[(waveN * 64 + ni * 16) * BK + aoff];

#pragma unroll
        for (int mi = 0; mi < 4; ++mi)
#pragma unroll
            for (int ni = 0; ni < 4; ++ni)
                acc[mi][ni] = __builtin_amdgcn_mfma_f32_16x16x32_bf16(af[mi], bfr[ni],
                                                                      acc[mi][ni], 0, 0, 0);
    }

    // epilogue: C/D layout col=lane&15, row=quad*4+reg
#pragma unroll
    for (int ni = 0; ni < 4; ++ni) {
        const int col = n0 + waveN * 64 + ni * 16 + l15;
        const float bv = bias[col];
#pragma unroll
        for (int mi = 0; mi < 4; ++mi) {
            const int row = m0 + waveM * 64 + mi * 16 + quad * 4;
            float* op = C + (size_t)row * N + col;
#pragma unroll
            for (int j = 0; j < 4; ++j)
                op[(size_t)j * N] = acc[mi][ni][j] + bv;
        }
    }
}

extern "C" void kernel_launch(void* const* d_in, const int* in_sizes, int n_in,
                              void* d_out, int out_size, void* d_ws, size_t ws_size,
                              hipStream_t stream) {
    const float* x  = (const float*)d_in[0];   // [4,2048,4096]
    const float* w  = (const float*)d_in[1];   // [4096,4096]  (out,in)
    const float* b  = (const float*)d_in[2];   // [4096]
    const float* la = (const float*)d_in[3];   // [4096,16]
    const float* lb = (const float*)d_in[4];   // [16,4096]
    float* out = (float*)d_out;

    const int M = in_sizes[0] / FEATURE_IN;    // 8192
    const int K = FEATURE_IN;
    const int N = FEATURE_OUT;

    uint16_t* xb = (uint16_t*)d_ws;                                  // M*K bf16 = 64 MiB
    uint16_t* wf = (uint16_t*)((char*)d_ws + (size_t)M * K * 2);     // N*K bf16 = 32 MiB

    // 1) x -> bf16
    {
        int nThreads = M * K / 8;
        cvt_x_bf16<<<nThreads / 256, 256, 0, stream>>>((const float4*)x, xb);
    }
    // 2) fold LoRA into weights (bf16)
    {
        int nThreads = N * K / 8;
        fuse_w_kernel<<<nThreads / 256, 256, 0, stream>>>(w, la, lb, wf);
    }
    // 3) GEMM + bias
    {
        dim3 grid(N / BN, M / BM);   // (32, 64)
        gemm_bt<<<grid, 256, 0, stream>>>(xb, wf, b, out, M, N, K);
    }
}

// Round 2
// 649.769 us; speedup vs baseline: 1.1034x; 1.1034x over previous
//
#include <hip/hip_runtime.h>
#include <cstdint>
#include <cstddef>

#define FEATURE_IN 4096
#define FEATURE_OUT 4096
#define RNK 16

typedef __bf16 bf16x8_t __attribute__((ext_vector_type(8)));
typedef float f32x4_t __attribute__((ext_vector_type(4)));

// ---------------- kernel 1: x fp32 -> bf16 (8 elems/thread, 16B ld/st) -------
__global__ __launch_bounds__(256) void cvt_x_bf16(const float4* __restrict__ x,
                                                  uint16_t* __restrict__ y) {
    int i = blockIdx.x * blockDim.x + threadIdx.x;
    float4 v0 = x[2 * i];
    float4 v1 = x[2 * i + 1];
    bf16x8_t o;
    o[0] = (__bf16)v0.x; o[1] = (__bf16)v0.y; o[2] = (__bf16)v0.z; o[3] = (__bf16)v0.w;
    o[4] = (__bf16)v1.x; o[5] = (__bf16)v1.y; o[6] = (__bf16)v1.z; o[7] = (__bf16)v1.w;
    ((bf16x8_t*)y)[i] = o;
}

// -------- kernel 2: Wf[n,k] = bf16(W[n,k] + 2*sum_r A[k,r]*B[r,n]) ----------
// Tiled rewrite: block handles 128k x 32n. la/lb staged in LDS (coalesced);
// la consumed via wave-broadcast LDS reads (same-address across n-lanes = free).
// Old version did stride-512B global gathers on la -> ~64 line-requests/instr.
#define FW_KB 128
#define FW_NB 32

__global__ __launch_bounds__(256) void fuse_w2(const float* __restrict__ w,
                                               const float* __restrict__ la,
                                               const float* __restrict__ lb,
                                               uint16_t* __restrict__ wf) {
    __shared__ float las[FW_KB * RNK];     // [k][r], 8 KB
    __shared__ float lbs[RNK * FW_NB];     // [r][n], 2 KB

    const int kb = blockIdx.x * FW_KB;
    const int nb = blockIdx.y * FW_NB;
    const int tid = threadIdx.x;

    // stage la tile: 2048 contiguous floats = 512 float4
    {
        const float4* src = (const float4*)(la + (size_t)kb * RNK);
        float4* dst = (float4*)las;
        dst[tid] = src[tid];
        dst[tid + 256] = src[tid + 256];
    }
    // stage lb tile: 512 floats
#pragma unroll
    for (int f = tid; f < RNK * FW_NB; f += 256) {
        int r = f >> 5;
        int nl = f & 31;
        lbs[r * FW_NB + nl] = lb[(size_t)r * FEATURE_OUT + nb + nl];
    }
    __syncthreads();

    const int nl = tid >> 3;    // 0..31
    const int kq = tid & 7;     // 0..7, each covers 16 k

    f32x4_t bcol[4];
#pragma unroll
    for (int r4 = 0; r4 < 4; ++r4) {
        f32x4_t v;
#pragma unroll
        for (int j = 0; j < 4; ++j) v[j] = lbs[(r4 * 4 + j) * FW_NB + nl];
        bcol[r4] = v;
    }

    const float4* las4 = (const float4*)las;   // index k*4 + r4
    const float* wrow = w + (size_t)(nb + nl) * FEATURE_IN + kb + kq * 16;
    uint16_t* wfrow = wf + (size_t)(nb + nl) * FEATURE_IN + kb + kq * 16;

#pragma unroll
    for (int h = 0; h < 2; ++h) {          // two groups of 8 k
        float4 wv0 = ((const float4*)wrow)[h * 2 + 0];
        float4 wv1 = ((const float4*)wrow)[h * 2 + 1];
        float wfv[8] = {wv0.x, wv0.y, wv0.z, wv0.w, wv1.x, wv1.y, wv1.z, wv1.w};
        bf16x8_t o;
#pragma unroll
        for (int j = 0; j < 8; ++j) {
            const int k = kq * 16 + h * 8 + j;
            float s = 0.f;
#pragma unroll
            for (int r4 = 0; r4 < 4; ++r4) {
                f32x4_t av = ((const f32x4_t*)las4)[k * 4 + r4];
                f32x4_t bv = bcol[r4];
                s += av[0] * bv[0] + av[1] * bv[1] + av[2] * bv[2] + av[3] * bv[3];
            }
            o[j] = (__bf16)(wfv[j] + 2.f * s);
        }
        ((bf16x8_t*)wfrow)[h] = o;
    }
}

// -------- kernel 3: C[M,N] = Xb[M,K] * Wf[N,K]^T + bias, fp32 out -----------
// m97 structure: 128x128 tile, BK=32, 4 waves (2x2), 4x4 MFMA 16x16x32 each,
// global_load_lds width=16 staging. (unchanged from round 1 — at plateau)
#define BM 128
#define BN 128
#define BK 32

__global__ __launch_bounds__(256) void gemm_bt(const uint16_t* __restrict__ Au,
                                               const uint16_t* __restrict__ Bu,
                                               const float* __restrict__ bias,
                                               float* __restrict__ C,
                                               int M, int N, int K) {
    __shared__ __bf16 As[BM * BK];   // [m][k], row-major, unpadded (global_load_lds layout)
    __shared__ __bf16 Bs[BN * BK];   // [n][k]

    const __bf16* A = (const __bf16*)Au;
    const __bf16* B = (const __bf16*)Bu;

    const int wv    = threadIdx.x >> 6;
    const int lane  = threadIdx.x & 63;
    const int waveM = wv >> 1;           // 0..1
    const int waveN = wv & 1;            // 0..1
    const int m0 = blockIdx.y * BM;
    const int n0 = blockIdx.x * BN;

    const int rowInCall = lane >> 2;
    const int kOff      = (lane & 3) * 8;

    const int l15  = lane & 15;
    const int quad = lane >> 4;
    const int aoff = l15 * BK + quad * 8;

    f32x4_t acc[4][4];
#pragma unroll
    for (int mi = 0; mi < 4; ++mi)
#pragma unroll
        for (int ni = 0; ni < 4; ++ni)
            acc[mi][ni] = (f32x4_t)0.f;

    for (int k0 = 0; k0 < K; k0 += BK) {
        __syncthreads();
#pragma unroll
        for (int t = 0; t < 2; ++t) {
            const int c = wv * 2 + t;   // 0..7, wave-uniform
            const __bf16* ga = A + (size_t)(m0 + c * 16 + rowInCall) * K + (k0 + kOff);
            __builtin_amdgcn_global_load_lds((const __attribute__((address_space(1))) void*)ga,
                                             (__attribute__((address_space(3))) void*)&As[c * 512],
                                             16, 0, 0);
            const __bf16* gb = B + (size_t)(n0 + c * 16 + rowInCall) * K + (k0 + kOff);
            __builtin_amdgcn_global_load_lds((const __attribute__((address_space(1))) void*)gb,
                                             (__attribute__((address_space(3))) void*)&Bs[c * 512],
                                             16, 0, 0);
        }
        __syncthreads();

        bf16x8_t af[4], bfr[4];
#pragma unroll
        for (int mi = 0; mi < 4; ++mi)
            af[mi] = *(const bf16x8_t*)&As[(waveM * 64 + mi * 16) * BK + aoff];
#pragma unroll
        for (int ni = 0; ni < 4; ++ni)
            bfr[ni] = *(const bf16x8_t*)&Bs[(waveN * 64 + ni * 16) * BK + aoff];

#pragma unroll
        for (int mi = 0; mi < 4; ++mi)
#pragma unroll
            for (int ni = 0; ni < 4; ++ni)
                acc[mi][ni] = __builtin_amdgcn_mfma_f32_16x16x32_bf16(af[mi], bfr[ni],
                                                                      acc[mi][ni], 0, 0, 0);
    }

    // epilogue: C/D layout col=lane&15, row=quad*4+reg
#pragma unroll
    for (int ni = 0; ni < 4; ++ni) {
        const int col = n0 + waveN * 64 + ni * 16 + l15;
        const float bv = bias[col];
#pragma unroll
        for (int mi = 0; mi < 4; ++mi) {
            const int row = m0 + waveM * 64 + mi * 16 + quad * 4;
            float* op = C + (size_t)row * N + col;
#pragma unroll
            for (int j = 0; j < 4; ++j)
                op[(size_t)j * N] = acc[mi][ni][j] + bv;
        }
    }
}

extern "C" void kernel_launch(void* const* d_in, const int* in_sizes, int n_in,
                              void* d_out, int out_size, void* d_ws, size_t ws_size,
                              hipStream_t stream) {
    const float* x  = (const float*)d_in[0];   // [4,2048,4096]
    const float* w  = (const float*)d_in[1];   // [4096,4096]  (out,in)
    const float* b  = (const float*)d_in[2];   // [4096]
    const float* la = (const float*)d_in[3];   // [4096,16]
    const float* lb = (const float*)d_in[4];   // [16,4096]
    float* out = (float*)d_out;

    const int M = in_sizes[0] / FEATURE_IN;    // 8192
    const int K = FEATURE_IN;
    const int N = FEATURE_OUT;

    uint16_t* xb = (uint16_t*)d_ws;                                  // M*K bf16 = 64 MiB
    uint16_t* wf = (uint16_t*)((char*)d_ws + (size_t)M * K * 2);     // N*K bf16 = 32 MiB

    // 1) x -> bf16
    {
        int nThreads = M * K / 8;
        cvt_x_bf16<<<nThreads / 256, 256, 0, stream>>>((const float4*)x, xb);
    }
    // 2) fold LoRA into weights (bf16), tiled/coalesced
    {
        dim3 grid(K / FW_KB, N / FW_NB);   // (32, 128)
        fuse_w2<<<grid, 256, 0, stream>>>(w, la, lb, wf);
    }
    // 3) GEMM + bias
    {
        dim3 grid(N / BN, M / BM);   // (32, 64)
        gemm_bt<<<grid, 256, 0, stream>>>(xb, wf, b, out, M, N, K);
    }
}

// Round 3
// 625.281 us; speedup vs baseline: 1.1466x; 1.0392x over previous
//
#include <hip/hip_runtime.h>
#include <cstdint>
#include <cstddef>

#define FEATURE_IN 4096
#define FEATURE_OUT 4096
#define RNK 16

typedef __bf16 bf16x8_t __attribute__((ext_vector_type(8)));
typedef float f32x4_t __attribute__((ext_vector_type(4)));

// ============ prep kernel: blocks [0,NCVT) convert x fp32->bf16;
//              blocks [NCVT, NCVT+NFUSE) fold LoRA into W (bf16) =============
#define FW_KB 128
#define FW_NB 32
#define NCVT 16384            // M*K/8/256 = 8192*4096/2048
#define NFUSE 4096            // (K/FW_KB)*(N/FW_NB) = 32*128

__global__ __launch_bounds__(256) void prep_kernel(const float* __restrict__ x,
                                                   uint16_t* __restrict__ xb,
                                                   const float* __restrict__ w,
                                                   const float* __restrict__ la,
                                                   const float* __restrict__ lb,
                                                   uint16_t* __restrict__ wf) {
    __shared__ float las[FW_KB * RNK];     // [k][r], 8 KB
    __shared__ float lbs[RNK * FW_NB];     // [r][n], 2 KB

    const int tid = threadIdx.x;

    if (blockIdx.x < NCVT) {
        // ---- x fp32 -> bf16, 8 elems/thread ----
        int i = blockIdx.x * 256 + tid;
        const float4* xp = (const float4*)x;
        float4 v0 = xp[2 * i];
        float4 v1 = xp[2 * i + 1];
        bf16x8_t o;
        o[0] = (__bf16)v0.x; o[1] = (__bf16)v0.y; o[2] = (__bf16)v0.z; o[3] = (__bf16)v0.w;
        o[4] = (__bf16)v1.x; o[5] = (__bf16)v1.y; o[6] = (__bf16)v1.z; o[7] = (__bf16)v1.w;
        ((bf16x8_t*)xb)[i] = o;
        return;
    }

    // ---- Wf[n,k] = bf16(W[n,k] + 2*sum_r A[k,r]*B[r,n]), 128k x 32n tile ----
    const int bid = blockIdx.x - NCVT;
    const int kb = (bid & 31) * FW_KB;
    const int nb = (bid >> 5) * FW_NB;

    {
        const float4* src = (const float4*)(la + (size_t)kb * RNK);
        float4* dst = (float4*)las;
        dst[tid] = src[tid];
        dst[tid + 256] = src[tid + 256];
    }
#pragma unroll
    for (int f = tid; f < RNK * FW_NB; f += 256) {
        int r = f >> 5;
        int nl = f & 31;
        lbs[r * FW_NB + nl] = lb[(size_t)r * FEATURE_OUT + nb + nl];
    }
    __syncthreads();

    const int nl = tid >> 3;    // 0..31
    const int kq = tid & 7;     // 0..7, each covers 16 k

    f32x4_t bcol[4];
#pragma unroll
    for (int r4 = 0; r4 < 4; ++r4) {
        f32x4_t v;
#pragma unroll
        for (int j = 0; j < 4; ++j) v[j] = lbs[(r4 * 4 + j) * FW_NB + nl];
        bcol[r4] = v;
    }

    const f32x4_t* las4 = (const f32x4_t*)las;   // index k*4 + r4
    const float* wrow = w + (size_t)(nb + nl) * FEATURE_IN + kb + kq * 16;
    uint16_t* wfrow = wf + (size_t)(nb + nl) * FEATURE_IN + kb + kq * 16;

#pragma unroll
    for (int h = 0; h < 2; ++h) {          // two groups of 8 k
        float4 wv0 = ((const float4*)wrow)[h * 2 + 0];
        float4 wv1 = ((const float4*)wrow)[h * 2 + 1];
        float wfv[8] = {wv0.x, wv0.y, wv0.z, wv0.w, wv1.x, wv1.y, wv1.z, wv1.w};
        bf16x8_t o;
#pragma unroll
        for (int j = 0; j < 8; ++j) {
            const int k = kq * 16 + h * 8 + j;
            float s = 0.f;
#pragma unroll
            for (int rr = 0; rr < 4; ++rr) {
                const int r4 = (rr + kq) & 3;   // rotated -> lanes hit different bank groups
                f32x4_t av = las4[k * 4 + r4];
                f32x4_t bv = bcol[r4];
                s += av[0] * bv[0] + av[1] * bv[1] + av[2] * bv[2] + av[3] * bv[3];
            }
            o[j] = (__bf16)(wfv[j] + 2.f * s);
        }
        ((bf16x8_t*)wfrow)[h] = o;
    }
}

// -------- GEMM: C[M,N] = Xb[M,K] * Wf[N,K]^T + bias, fp32 out ---------------
// m97 structure: 128x128 tile, BK=32, 4 waves (2x2), 4x4 MFMA 16x16x32.
// Round 3: strength-reduced staging addresses (hoisted pointers, +BK bumps)
// to cut the ~21 v_lshl_add_u64/iter the compiler otherwise emits.
#define BM 128
#define BN 128
#define BK 32

__global__ __launch_bounds__(256) void gemm_bt(const uint16_t* __restrict__ Au,
                                               const uint16_t* __restrict__ Bu,
                                               const float* __restrict__ bias,
                                               float* __restrict__ C,
                                               int M, int N, int K) {
    __shared__ __bf16 As[BM * BK];   // [m][k], unpadded (global_load_lds layout)
    __shared__ __bf16 Bs[BN * BK];   // [n][k]

    const __bf16* A = (const __bf16*)Au;
    const __bf16* B = (const __bf16*)Bu;

    const int wv    = threadIdx.x >> 6;
    const int lane  = threadIdx.x & 63;
    const int waveM = wv >> 1;           // 0..1
    const int waveN = wv & 1;            // 0..1
    const int m0 = blockIdx.y * BM;
    const int n0 = blockIdx.x * BN;

    const int rowInCall = lane >> 2;
    const int kOff      = (lane & 3) * 8;

    const int l15  = lane & 15;
    const int quad = lane >> 4;
    const int aoff = l15 * BK + quad * 8;

    // hoisted staging pointers (bumped by +BK per K-iter)
    const int c0 = wv * 2, c1 = wv * 2 + 1;
    const __bf16* ga0 = A + (size_t)(m0 + c0 * 16 + rowInCall) * K + kOff;
    const __bf16* ga1 = A + (size_t)(m0 + c1 * 16 + rowInCall) * K + kOff;
    const __bf16* gb0 = B + (size_t)(n0 + c0 * 16 + rowInCall) * K + kOff;
    const __bf16* gb1 = B + (size_t)(n0 + c1 * 16 + rowInCall) * K + kOff;
    auto* asDst0 = (__attribute__((address_space(3))) void*)&As[c0 * 512];
    auto* asDst1 = (__attribute__((address_space(3))) void*)&As[c1 * 512];
    auto* bsDst0 = (__attribute__((address_space(3))) void*)&Bs[c0 * 512];
    auto* bsDst1 = (__attribute__((address_space(3))) void*)&Bs[c1 * 512];

    f32x4_t acc[4][4];
#pragma unroll
    for (int mi = 0; mi < 4; ++mi)
#pragma unroll
        for (int ni = 0; ni < 4; ++ni)
            acc[mi][ni] = (f32x4_t)0.f;

    for (int k0 = 0; k0 < K; k0 += BK) {
        __syncthreads();
        __builtin_amdgcn_global_load_lds((const __attribute__((address_space(1))) void*)ga0,
                                         asDst0, 16, 0, 0);
        __builtin_amdgcn_global_load_lds((const __attribute__((address_space(1))) void*)ga1,
                                         asDst1, 16, 0, 0);
        __builtin_amdgcn_global_load_lds((const __attribute__((address_space(1))) void*)gb0,
                                         bsDst0, 16, 0, 0);
        __builtin_amdgcn_global_load_lds((const __attribute__((address_space(1))) void*)gb1,
                                         bsDst1, 16, 0, 0);
        ga0 += BK; ga1 += BK; gb0 += BK; gb1 += BK;
        __syncthreads();

        bf16x8_t af[4], bfr[4];
#pragma unroll
        for (int mi = 0; mi < 4; ++mi)
            af[mi] = *(const bf16x8_t*)&As[(waveM * 64 + mi * 16) * BK + aoff];
#pragma unroll
        for (int ni = 0; ni < 4; ++ni)
            bfr[ni] = *(const bf16x8_t*)&Bs[(waveN * 64 + ni * 16) * BK + aoff];

#pragma unroll
        for (int mi = 0; mi < 4; ++mi)
#pragma unroll
            for (int ni = 0; ni < 4; ++ni)
                acc[mi][ni] = __builtin_amdgcn_mfma_f32_16x16x32_bf16(af[mi], bfr[ni],
                                                                      acc[mi][ni], 0, 0, 0);
    }

    // epilogue: C/D layout col=lane&15, row=quad*4+reg
#pragma unroll
    for (int ni = 0; ni < 4; ++ni) {
        const int col = n0 + waveN * 64 + ni * 16 + l15;
        const float bv = bias[col];
#pragma unroll
        for (int mi = 0; mi < 4; ++mi) {
            const int row = m0 + waveM * 64 + mi * 16 + quad * 4;
            float* op = C + (size_t)row * N + col;
#pragma unroll
            for (int j = 0; j < 4; ++j)
                op[(size_t)j * N] = acc[mi][ni][j] + bv;
        }
    }
}

extern "C" void kernel_launch(void* const* d_in, const int* in_sizes, int n_in,
                              void* d_out, int out_size, void* d_ws, size_t ws_size,
                              hipStream_t stream) {
    const float* x  = (const float*)d_in[0];   // [4,2048,4096]
    const float* w  = (const float*)d_in[1];   // [4096,4096]  (out,in)
    const float* b  = (const float*)d_in[2];   // [4096]
    const float* la = (const float*)d_in[3];   // [4096,16]
    const float* lb = (const float*)d_in[4];   // [16,4096]
    float* out = (float*)d_out;

    const int M = in_sizes[0] / FEATURE_IN;    // 8192
    const int K = FEATURE_IN;
    const int N = FEATURE_OUT;

    uint16_t* xb = (uint16_t*)d_ws;                                  // M*K bf16 = 64 MiB
    uint16_t* wf = (uint16_t*)((char*)d_ws + (size_t)M * K * 2);     // N*K bf16 = 32 MiB

    // 1) fused prep: x->bf16 + LoRA-folded W->bf16 (one dispatch)
    prep_kernel<<<NCVT + NFUSE, 256, 0, stream>>>(x, xb, w, la, lb, wf);

    // 2) GEMM + bias
    {
        dim3 grid(N / BN, M / BM);   // (32, 64)
        gemm_bt<<<grid, 256, 0, stream>>>(xb, wf, b, out, M, N, K);
    }
}